// Round 3
// baseline (1152.910 us; speedup 1.0000x reference)
//
#include <hip/hip_runtime.h>

typedef unsigned short u16;
typedef unsigned int u32;
typedef __attribute__((ext_vector_type(8)))  __bf16 bf16x8;
typedef __attribute__((ext_vector_type(8)))  u16    u16x8;
typedef __attribute__((ext_vector_type(16))) float  f32x16;

#define NPTS 131072
#define DIM  256
#define KC   2048

// global -> LDS direct DMA, 16B per lane (wave-uniform base + lane*16)
#define GLD_LDS16(gsrc, ldst) \
    __builtin_amdgcn_global_load_lds( \
        (const __attribute__((address_space(1))) void*)(gsrc), \
        (__attribute__((address_space(3))) void*)(ldst), 16, 0, 0)

__device__ inline u16 bf16_rne(float f) {
    u32 u = __builtin_bit_cast(u32, f);
    u32 r = u + 0x7fffu + ((u >> 16) & 1u);
    return (u16)(r >> 16);
}
__device__ inline float bf16_to_f32(u16 h) {
    u32 u = ((u32)h) << 16;
    return __builtin_bit_cast(float, u);
}

// ---------------------------------------------------------------------------
// Centroid prep: split into bf16 hi/lo in MFMA-A-fragment order + ||c||^2.
// Also zeroes the global histogram (blocks 0..7).
// ---------------------------------------------------------------------------
__global__ void cprep_kernel(const float* __restrict__ cen,
                             u16* __restrict__ c_frag,
                             float* __restrict__ c_sq,
                             int* __restrict__ hist) {
    if (blockIdx.x < 8) hist[blockIdx.x * 256 + threadIdx.x] = 0;
    const int lane = threadIdx.x & 63;
    const int wv   = threadIdx.x >> 6;
    const int n    = blockIdx.x * 4 + wv;              // centroid row
    float4 v = ((const float4*)(cen + (size_t)n * DIM))[lane];  // dims lane*4..+3
    float ss = v.x * v.x + v.y * v.y + v.z * v.z + v.w * v.w;
    float fv[4] = {v.x, v.y, v.z, v.w};
    u16 hh[4], ll[4];
#pragma unroll
    for (int j = 0; j < 4; ++j) {
        hh[j] = bf16_rne(fv[j]);
        ll[j] = bf16_rne(fv[j] - bf16_to_f32(hh[j]));
    }
    const int g = n >> 5, r32 = n & 31;
    const int s = lane >> 1;
    const int j0 = (lane & 1) * 4;
    const size_t base = ((size_t)((g * 32 + s) * 32 + r32)) * 8 + j0;
    uint2 h2, l2;
    h2.x = (u32)hh[0] | ((u32)hh[1] << 16); h2.y = (u32)hh[2] | ((u32)hh[3] << 16);
    l2.x = (u32)ll[0] | ((u32)ll[1] << 16); l2.y = (u32)ll[2] | ((u32)ll[3] << 16);
    *(uint2*)(c_frag + base) = h2;
    *(uint2*)(c_frag + (size_t)KC * DIM + base) = l2;
#pragma unroll
    for (int off = 32; off > 0; off >>= 1) ss += __shfl_xor(ss, off);
    if (lane == 0) c_sq[n] = ss;
}

// ---------------------------------------------------------------------------
// Assignment: per wave, 32 points, 3-term split-bf16 MFMA over all 2048
// centroids, argmin in registers. Single 32KB LDS tile fed by
// global_load_lds (no staging VGPRs) -> 3 blocks/CU. Fused LDS histogram.
// ---------------------------------------------------------------------------
__global__ __launch_bounds__(256, 3) void assign_kernel(
    const float* __restrict__ x, const u16* __restrict__ c_frag,
    const float* __restrict__ c_sq, int* __restrict__ assigns,
    int* __restrict__ hist) {
    __shared__ u16 lds_c[16384];   // hi 16KB @0, lo 16KB @8192
    __shared__ int lh[KC];         // 8KB block-local histogram

    const int tid  = threadIdx.x;
    const int lane = tid & 63;
    const int wv   = tid >> 6;
    const int l31  = lane & 31;
    const int kh   = lane >> 5;

#pragma unroll
    for (int i = 0; i < KC / 256; ++i) lh[tid + 256 * i] = 0;

    // ---- load + split this lane's x half-row into 16 hi/lo fragments ----
    const int m = blockIdx.x * 128 + wv * 32 + l31;
    const float4* xr = (const float4*)(x + (size_t)m * DIM);
    bf16x8 xh[16], xl[16];
#pragma unroll
    for (int kt = 0; kt < 16; ++kt) {
        float4 a0 = xr[kt * 4 + kh * 2];
        float4 a1 = xr[kt * 4 + kh * 2 + 1];
        float fv[8] = {a0.x, a0.y, a0.z, a0.w, a1.x, a1.y, a1.z, a1.w};
        u16x8 uh, ul;
#pragma unroll
        for (int j = 0; j < 8; ++j) {
            u16 h = bf16_rne(fv[j]);
            uh[j] = h;
            ul[j] = bf16_rne(fv[j] - bf16_to_f32(h));
        }
        xh[kt] = __builtin_bit_cast(bf16x8, uh);
        xl[kt] = __builtin_bit_cast(bf16x8, ul);
    }

    const float4* csq4 = (const float4*)c_sq;
    float best = 3.4e38f;
    int bidx = 0;

    for (int nt = 0; nt < 64; ++nt) {
        __syncthreads();   // WAR: all waves done reading previous tile
        const u16* src_h = c_frag + (size_t)nt * 8192;
        const u16* src_l = c_frag + (size_t)KC * DIM + (size_t)nt * 8192;
#pragma unroll
        for (int i = 0; i < 4; ++i) {
            GLD_LDS16(src_h + (tid + 256 * i) * 8, lds_c + (tid + 256 * i) * 8);
            GLD_LDS16(src_l + (tid + 256 * i) * 8, lds_c + 8192 + (tid + 256 * i) * 8);
        }
        __syncthreads();   // RAW: compiler drains vmcnt before barrier

        f32x16 acc;
#pragma unroll
        for (int r = 0; r < 16; ++r) acc[r] = 0.0f;
#pragma unroll
        for (int kt = 0; kt < 16; ++kt) {
            const int off = ((kt * 2 + kh) * 32 + l31) * 8;
            bf16x8 ch = *(const bf16x8*)(lds_c + off);
            bf16x8 cl = *(const bf16x8*)(lds_c + 8192 + off);
            acc = __builtin_amdgcn_mfma_f32_32x32x16_bf16(ch, xh[kt], acc, 0, 0, 0);
            acc = __builtin_amdgcn_mfma_f32_32x32x16_bf16(ch, xl[kt], acc, 0, 0, 0);
            acc = __builtin_amdgcn_mfma_f32_32x32x16_bf16(cl, xh[kt], acc, 0, 0, 0);
        }

        // score = 0.5*||c||^2 - dot ; D row = (reg&3) + 8*(reg>>2) + 4*kh
#pragma unroll
        for (int b = 0; b < 4; ++b) {
            float4 cs = csq4[nt * 8 + 2 * b + kh];
            const int n0 = nt * 32 + 8 * b + 4 * kh;
            float v0 = 0.5f * cs.x - acc[b * 4 + 0];
            float v1 = 0.5f * cs.y - acc[b * 4 + 1];
            float v2 = 0.5f * cs.z - acc[b * 4 + 2];
            float v3 = 0.5f * cs.w - acc[b * 4 + 3];
            if (v0 < best) { best = v0; bidx = n0; }
            if (v1 < best) { best = v1; bidx = n0 + 1; }
            if (v2 < best) { best = v2; bidx = n0 + 2; }
            if (v3 < best) { best = v3; bidx = n0 + 3; }
        }
    }

    // merge the lane pair holding the other 16 centroid rows for point m
    float oval = __shfl_xor(best, 32);
    int   oidx = __shfl_xor(bidx, 32);
    if (oval < best || (oval == best && oidx < bidx)) { best = oval; bidx = oidx; }
    if (lane < 32) {
        assigns[m] = bidx;
        atomicAdd(&lh[bidx], 1);
    }
    __syncthreads();
#pragma unroll
    for (int i = 0; i < KC / 256; ++i) {
        int v = lh[tid + 256 * i];
        if (v) atomicAdd(&hist[tid + 256 * i], v);
    }
}

// Exclusive prefix sum over KC=2048 counts; one block of 256 threads x 8 each.
__global__ void scan_kernel(const int* __restrict__ hist,
                            int* __restrict__ base_,
                            int* __restrict__ cursor) {
    __shared__ int tmp[256];
    const int tid = threadIdx.x;
    int v[8], s = 0;
#pragma unroll
    for (int j = 0; j < 8; ++j) { v[j] = hist[tid * 8 + j]; s += v[j]; }
    tmp[tid] = s;
    __syncthreads();
    for (int off = 1; off < 256; off <<= 1) {
        int t = (tid >= off) ? tmp[tid - off] : 0;
        __syncthreads();
        tmp[tid] += t;
        __syncthreads();
    }
    int ex = tmp[tid] - s;
#pragma unroll
    for (int j = 0; j < 8; ++j) {
        base_[tid * 8 + j] = ex;
        cursor[tid * 8 + j] = ex;
        ex += v[j];
    }
}

__global__ void reorder_kernel(const int* __restrict__ assigns,
                               int* __restrict__ cursor,
                               int* __restrict__ order) {
    const int p = blockIdx.x * 256 + threadIdx.x;
    const int a = assigns[p];
    int pos = atomicAdd(&cursor[a], 1);
    order[pos] = p;
}

// One block per cluster: 4 waves stride the cluster's rows; float4 lanes.
// Fused finalize: writes the new centroid directly.
__global__ void reduce_kernel(const float* __restrict__ x,
                              const int* __restrict__ order,
                              const int* __restrict__ base_,
                              const int* __restrict__ hist,
                              const float* __restrict__ cen,
                              float* __restrict__ out) {
    __shared__ float4 red[256];
    const int tid = threadIdx.x;
    const int g = tid >> 6, l = tid & 63;     // wave id, lane
    const int k = blockIdx.x;
    const int s = base_[k], cnt = hist[k];
    float4 acc = {0.f, 0.f, 0.f, 0.f};
    int i = g;
    for (; i + 8 <= cnt; i += 8) {            // 2-deep per-wave unroll for MLP
        int p0 = order[s + i];
        int p1 = order[s + i + 4];
        float4 v0 = ((const float4*)(x + (size_t)p0 * DIM))[l];
        float4 v1 = ((const float4*)(x + (size_t)p1 * DIM))[l];
        acc.x += v0.x + v1.x; acc.y += v0.y + v1.y;
        acc.z += v0.z + v1.z; acc.w += v0.w + v1.w;
    }
    for (; i < cnt; i += 4) {
        int p = order[s + i];
        float4 v = ((const float4*)(x + (size_t)p * DIM))[l];
        acc.x += v.x; acc.y += v.y; acc.z += v.z; acc.w += v.w;
    }
    red[tid] = acc;
    __syncthreads();
    if (g == 0) {
        float4 a0 = red[l], a1 = red[64 + l], a2 = red[128 + l], a3 = red[192 + l];
        float4 o;
        o.x = a0.x + a1.x + a2.x + a3.x;
        o.y = a0.y + a1.y + a2.y + a3.y;
        o.z = a0.z + a1.z + a2.z + a3.z;
        o.w = a0.w + a1.w + a2.w + a3.w;
        if (cnt > 0) {
            float r = 1.0f / (float)cnt;
            o.x *= r; o.y *= r; o.z *= r; o.w *= r;
        } else {
            o = ((const float4*)(cen + (size_t)k * DIM))[l];
        }
        ((float4*)(out + (size_t)k * DIM))[l] = o;
    }
}

extern "C" void kernel_launch(void* const* d_in, const int* in_sizes, int n_in,
                              void* d_out, int out_size, void* d_ws, size_t ws_size,
                              hipStream_t stream) {
    (void)in_sizes; (void)n_in; (void)out_size; (void)ws_size;
    const float* x   = (const float*)d_in[0];
    const float* cen = (const float*)d_in[1];
    float* out = (float*)d_out;

    char* ws = (char*)d_ws;
    size_t off = 0;
    u16* c_frag = (u16*)(ws + off);          off += (size_t)2 * KC * DIM * 2;  // 2MB
    float* c_sq = (float*)(ws + off);        off += (size_t)KC * 4;            // 8KB
    int* assigns = (int*)(ws + off);         off += (size_t)NPTS * 4;          // 512KB
    int* hist = (int*)(ws + off);            off += (size_t)KC * 4;            // 8KB
    int* base_ = (int*)(ws + off);           off += (size_t)KC * 4;            // 8KB
    int* cursor = (int*)(ws + off);          off += (size_t)KC * 4;            // 8KB
    int* order = (int*)(ws + off);           off += (size_t)NPTS * 4;          // 512KB

    cprep_kernel<<<KC / 4, 256, 0, stream>>>(cen, c_frag, c_sq, hist);
    assign_kernel<<<NPTS / 128, 256, 0, stream>>>(x, c_frag, c_sq, assigns, hist);
    scan_kernel<<<1, 256, 0, stream>>>(hist, base_, cursor);
    reorder_kernel<<<NPTS / 256, 256, 0, stream>>>(assigns, cursor, order);
    reduce_kernel<<<KC, 256, 0, stream>>>(x, order, base_, hist, cen, out);
}

// Round 5
// 643.153 us; speedup vs baseline: 1.7926x; 1.7926x over previous
//
#include <hip/hip_runtime.h>

typedef unsigned short u16;
typedef unsigned int u32;
typedef __attribute__((ext_vector_type(4)))  int  i32x4;
typedef __attribute__((ext_vector_type(16))) int  i32x16;
typedef __attribute__((ext_vector_type(16))) char i8x16;

#define NPTS 131072
#define DIM  256
#define KC   2048

// 3-level fixed point: v = S1*q1 + S2*q2 + S3*q3 + eps, |eps| <= S3/2 ~ 4.8e-7
// Ratio 254 => rint(r*INV) in [-127,127]: no clamp cascade.
// Identity S1*S3 == S2*S2 lets q2q2, q1q3, q3q1 share one accumulator.
constexpr float S1  = 0.0625f;                 // 127*S1 = 7.94 > max|N(0,1)|
constexpr float S2  = S1 / 254.0f;
constexpr float S3  = S2 * S2 / S1;            // = S2/254
constexpr float IS1 = 16.0f;
constexpr float IS2 = 4064.0f;                 // 254/S1
constexpr float IS3 = 1.0f / S3;
constexpr float W_A = S1 * S1;
constexpr float W_B = S1 * S2;
constexpr float W_C = S2 * S2;                 // == S1*S3

__device__ inline void quant3(float v, char& q1, char& q2, char& q3) {
    float a = fminf(fmaxf(rintf(v * IS1), -127.f), 127.f);
    float r1 = fmaf(-a, S1, v);                // exact (pow2 scale)
    float b = fminf(fmaxf(rintf(r1 * IS2), -127.f), 127.f);
    float r2 = fmaf(-b, S2, r1);               // ~1-ulp error, absorbed by q3
    float c = fminf(fmaxf(rintf(r2 * IS3), -127.f), 127.f);
    q1 = (char)a; q2 = (char)b; q3 = (char)c;
}

// global -> LDS direct DMA, 16B per lane (wave-uniform base + lane*16)
#define GLD16(gsrc, ldst) \
    __builtin_amdgcn_global_load_lds( \
        (const __attribute__((address_space(1))) void*)(gsrc), \
        (__attribute__((address_space(3))) void*)(ldst), 16, 0, 0)

// ---------------------------------------------------------------------------
// Centroid prep: 3-level i8 split in MFMA-A-fragment order + ||c||^2.
// Per tile g (32 centroids): chunk s = dim/16, addr = ((g*16+s)*32+row)*16+b.
// Level l at byte offset l*KC*DIM. Also zeroes hist (blocks 0..7).
// ---------------------------------------------------------------------------
__global__ void cprep_kernel(const float* __restrict__ cen,
                             char* __restrict__ c_q,
                             float* __restrict__ c_sq,
                             int* __restrict__ hist) {
    if (blockIdx.x < 8) hist[blockIdx.x * 256 + threadIdx.x] = 0;
    const int lane = threadIdx.x & 63;
    const int wv   = threadIdx.x >> 6;
    const int n    = blockIdx.x * 4 + wv;               // centroid row
    float4 v = ((const float4*)(cen + (size_t)n * DIM))[lane];  // dims lane*4..+3
    float ss = v.x * v.x + v.y * v.y + v.z * v.z + v.w * v.w;
    float fv[4] = {v.x, v.y, v.z, v.w};
    char q1[4], q2[4], q3[4];
#pragma unroll
    for (int j = 0; j < 4; ++j) quant3(fv[j], q1[j], q2[j], q3[j]);
    const int g = n >> 5, r32 = n & 31;
    const int s = lane >> 2;                             // chunk = dim/16
    const size_t base = ((size_t)((g * 16 + s) * 32 + r32)) * 16 + (lane & 3) * 4;
    u32 p1 = (u32)(unsigned char)q1[0] | ((u32)(unsigned char)q1[1] << 8) |
             ((u32)(unsigned char)q1[2] << 16) | ((u32)(unsigned char)q1[3] << 24);
    u32 p2 = (u32)(unsigned char)q2[0] | ((u32)(unsigned char)q2[1] << 8) |
             ((u32)(unsigned char)q2[2] << 16) | ((u32)(unsigned char)q2[3] << 24);
    u32 p3 = (u32)(unsigned char)q3[0] | ((u32)(unsigned char)q3[1] << 8) |
             ((u32)(unsigned char)q3[2] << 16) | ((u32)(unsigned char)q3[3] << 24);
    *(u32*)(c_q + base) = p1;
    *(u32*)(c_q + (size_t)KC * DIM + base) = p2;
    *(u32*)(c_q + (size_t)2 * KC * DIM + base) = p3;
#pragma unroll
    for (int off = 32; off > 0; off >>= 1) ss += __shfl_xor(ss, off);
    if (lane == 0) c_sq[n] = ss;
}

// ---------------------------------------------------------------------------
// Assignment: per wave 32 points x all 2048 centroids, 6 i8 MFMAs per k-tile:
//   accA += q1c*q1x                        (weight S1^2)
//   accB += q1c*q2x + q2c*q1x              (weight S1*S2)
//   accC += q2c*q2x + q1c*q3x + q3c*q1x    (weight S2^2 == S1*S3)
// Double-buffered 24KB tiles via global_load_lds; prefetch issued right after
// the barrier so the whole compute phase hides it.
// ---------------------------------------------------------------------------
__global__ __launch_bounds__(256, 2) void assign_kernel(
    const float* __restrict__ x, const char* __restrict__ c_q,
    const float* __restrict__ c_sq, int* __restrict__ assigns,
    int* __restrict__ hist) {
    __shared__ char lds_c[2 * 24576];   // buf: [q1 8KB][q2 8KB][q3 8KB] x 2

    const int tid  = threadIdx.x;
    const int lane = tid & 63;
    const int wv   = tid >> 6;
    const int l31  = lane & 31;
    const int kh   = lane >> 5;         // 16-dim half of the 32-dim k-tile

    // ---- quantize this lane's point (dims kt*32+kh*16 .. +15 per kt) ----
    const int m = blockIdx.x * 128 + wv * 32 + l31;
    const float4* xr = (const float4*)(x + (size_t)m * DIM);
    i8x16 xq1[8], xq2[8], xq3[8];
#pragma unroll
    for (int kt = 0; kt < 8; ++kt) {
        float tmp[16];
#pragma unroll
        for (int j = 0; j < 4; ++j) {
            float4 f = xr[kt * 8 + kh * 4 + j];
            tmp[j * 4 + 0] = f.x; tmp[j * 4 + 1] = f.y;
            tmp[j * 4 + 2] = f.z; tmp[j * 4 + 3] = f.w;
        }
        i8x16 v1, v2, v3;
#pragma unroll
        for (int j = 0; j < 16; ++j) {
            char a, b, c;
            quant3(tmp[j], a, b, c);
            v1[j] = a; v2[j] = b; v3[j] = c;
        }
        xq1[kt] = v1; xq2[kt] = v2; xq3[kt] = v3;
    }

    const float4* csq4 = (const float4*)c_sq;
    float best = 3.4e38f;
    int bidx = 0;

    const char* cl2 = c_q + (size_t)KC * DIM;
    const char* cl3 = c_q + (size_t)2 * KC * DIM;
    // prologue: DMA tile 0 (6 x 16B per thread)
    {
        GLD16(c_q + tid * 16,         lds_c + tid * 16);
        GLD16(c_q + (tid + 256) * 16, lds_c + (tid + 256) * 16);
        GLD16(cl2 + tid * 16,         lds_c + 8192 + tid * 16);
        GLD16(cl2 + (tid + 256) * 16, lds_c + 8192 + (tid + 256) * 16);
        GLD16(cl3 + tid * 16,         lds_c + 16384 + tid * 16);
        GLD16(cl3 + (tid + 256) * 16, lds_c + 16384 + (tid + 256) * 16);
    }

    for (int nt = 0; nt < 64; ++nt) {
        const int b = nt & 1;
        __syncthreads();   // drains own DMA (vmcnt 0) -> tile nt visible to all
        if (nt < 63) {     // prefetch nt+1 into other buffer; hidden by compute
            const size_t so = (size_t)(nt + 1) * 8192;
            char* d = lds_c + (b ^ 1) * 24576;
            GLD16(c_q + so + tid * 16,         d + tid * 16);
            GLD16(c_q + so + (tid + 256) * 16, d + (tid + 256) * 16);
            GLD16(cl2 + so + tid * 16,         d + 8192 + tid * 16);
            GLD16(cl2 + so + (tid + 256) * 16, d + 8192 + (tid + 256) * 16);
            GLD16(cl3 + so + tid * 16,         d + 16384 + tid * 16);
            GLD16(cl3 + so + (tid + 256) * 16, d + 16384 + (tid + 256) * 16);
        }

        i32x16 accA = {}, accB = {}, accC = {};
        const char* cb = lds_c + b * 24576;
#pragma unroll
        for (int kt = 0; kt < 8; ++kt) {
            const int off = ((kt * 2 + kh) * 32 + l31) * 16;
            i32x4 c1 = __builtin_bit_cast(i32x4, *(const i8x16*)(cb + off));
            i32x4 c2 = __builtin_bit_cast(i32x4, *(const i8x16*)(cb + 8192 + off));
            i32x4 c3 = __builtin_bit_cast(i32x4, *(const i8x16*)(cb + 16384 + off));
            i32x4 x1 = __builtin_bit_cast(i32x4, xq1[kt]);
            i32x4 x2 = __builtin_bit_cast(i32x4, xq2[kt]);
            i32x4 x3 = __builtin_bit_cast(i32x4, xq3[kt]);
            accA = __builtin_amdgcn_mfma_i32_32x32x32_i8(c1, x1, accA, 0, 0, 0);
            accB = __builtin_amdgcn_mfma_i32_32x32x32_i8(c1, x2, accB, 0, 0, 0);
            accB = __builtin_amdgcn_mfma_i32_32x32x32_i8(c2, x1, accB, 0, 0, 0);
            accC = __builtin_amdgcn_mfma_i32_32x32x32_i8(c2, x2, accC, 0, 0, 0);
            accC = __builtin_amdgcn_mfma_i32_32x32x32_i8(c1, x3, accC, 0, 0, 0);
            accC = __builtin_amdgcn_mfma_i32_32x32x32_i8(c3, x1, accC, 0, 0, 0);
        }

        // score = 0.5*||c||^2 - dot ; D row = (reg&3) + 8*(reg>>2) + 4*kh
#pragma unroll
        for (int bq = 0; bq < 4; ++bq) {
            float4 cs = csq4[nt * 8 + 2 * bq + kh];
            const int n0 = nt * 32 + 8 * bq + 4 * kh;
            float csa[4] = {cs.x, cs.y, cs.z, cs.w};
#pragma unroll
            for (int r = 0; r < 4; ++r) {
                const int idx = bq * 4 + r;
                float dot = (float)accA[idx] * W_A + (float)accB[idx] * W_B +
                            (float)accC[idx] * W_C;
                float v = 0.5f * csa[r] - dot;
                if (v < best) { best = v; bidx = n0 + r; }
            }
        }
    }

    // merge the lane pair holding the other 16 centroid rows for point m
    float oval = __shfl_xor(best, 32);
    int   oidx = __shfl_xor(bidx, 32);
    if (oval < best || (oval == best && oidx < bidx)) { best = oval; bidx = oidx; }
    if (lane < 32) {
        assigns[m] = bidx;
        atomicAdd(&hist[bidx], 1);   // 128 atomics/block; LDS staging gains nothing
    }
}

// Exclusive prefix sum over KC=2048 counts; one block of 256 threads x 8 each.
__global__ void scan_kernel(const int* __restrict__ hist,
                            int* __restrict__ base_,
                            int* __restrict__ cursor) {
    __shared__ int tmp[256];
    const int tid = threadIdx.x;
    int v[8], s = 0;
#pragma unroll
    for (int j = 0; j < 8; ++j) { v[j] = hist[tid * 8 + j]; s += v[j]; }
    tmp[tid] = s;
    __syncthreads();
    for (int off = 1; off < 256; off <<= 1) {
        int t = (tid >= off) ? tmp[tid - off] : 0;
        __syncthreads();
        tmp[tid] += t;
        __syncthreads();
    }
    int ex = tmp[tid] - s;
#pragma unroll
    for (int j = 0; j < 8; ++j) {
        base_[tid * 8 + j] = ex;
        cursor[tid * 8 + j] = ex;
        ex += v[j];
    }
}

__global__ void reorder_kernel(const int* __restrict__ assigns,
                               int* __restrict__ cursor,
                               int* __restrict__ order) {
    const int p = blockIdx.x * 256 + threadIdx.x;
    const int a = assigns[p];
    int pos = atomicAdd(&cursor[a], 1);
    order[pos] = p;
}

// ---------------------------------------------------------------------------
// Skew-immune segmented reduce: each block owns 256 consecutive rows of the
// SORTED order array; thread t owns dim t (coalesced 1KB row reads). Flush to
// sums[] with atomics only at cluster boundaries (block-uniform branches).
// ---------------------------------------------------------------------------
__global__ void reduce_kernel(const float* __restrict__ x,
                              const int* __restrict__ order,
                              const int* __restrict__ assigns,
                              float* __restrict__ sums) {
    const int tid = threadIdx.x;
    const int r0 = blockIdx.x * 256;
    float acc = 0.f;
    int cur = assigns[order[r0]];
    for (int r = 0; r < 256; r += 4) {
        int p0 = order[r0 + r + 0], p1 = order[r0 + r + 1];
        int p2 = order[r0 + r + 2], p3 = order[r0 + r + 3];
        float v0 = x[(size_t)p0 * DIM + tid];
        float v1 = x[(size_t)p1 * DIM + tid];
        float v2 = x[(size_t)p2 * DIM + tid];
        float v3 = x[(size_t)p3 * DIM + tid];
        int a0 = assigns[p0], a1 = assigns[p1], a2 = assigns[p2], a3 = assigns[p3];
        if (a0 != cur) { unsafeAtomicAdd(&sums[(size_t)cur * DIM + tid], acc); acc = 0.f; cur = a0; }
        acc += v0;
        if (a1 != cur) { unsafeAtomicAdd(&sums[(size_t)cur * DIM + tid], acc); acc = 0.f; cur = a1; }
        acc += v1;
        if (a2 != cur) { unsafeAtomicAdd(&sums[(size_t)cur * DIM + tid], acc); acc = 0.f; cur = a2; }
        acc += v2;
        if (a3 != cur) { unsafeAtomicAdd(&sums[(size_t)cur * DIM + tid], acc); acc = 0.f; cur = a3; }
        acc += v3;
    }
    unsafeAtomicAdd(&sums[(size_t)cur * DIM + tid], acc);
}

__global__ void finalize_kernel(const float* __restrict__ sums,
                                const int* __restrict__ hist,
                                const float* __restrict__ cen,
                                float* __restrict__ out) {
    const int id = blockIdx.x * 256 + threadIdx.x;   // KC*64 items
    const int k = id >> 6;
    const int cnt = hist[k];
    float4 s = ((const float4*)sums)[id];
    float4 c = ((const float4*)cen)[id];
    float4 o;
    if (cnt > 0) {
        float r = 1.0f / (float)cnt;
        o.x = s.x * r; o.y = s.y * r; o.z = s.z * r; o.w = s.w * r;
    } else {
        o = c;
    }
    ((float4*)out)[id] = o;
}

extern "C" void kernel_launch(void* const* d_in, const int* in_sizes, int n_in,
                              void* d_out, int out_size, void* d_ws, size_t ws_size,
                              hipStream_t stream) {
    (void)in_sizes; (void)n_in; (void)out_size; (void)ws_size;
    const float* x   = (const float*)d_in[0];
    const float* cen = (const float*)d_in[1];
    float* out = (float*)d_out;

    char* ws = (char*)d_ws;
    size_t off = 0;
    char* c_q = (char*)(ws + off);           off += (size_t)3 * KC * DIM;      // 1.5MB
    float* c_sq = (float*)(ws + off);        off += (size_t)KC * 4;            // 8KB
    int* assigns = (int*)(ws + off);         off += (size_t)NPTS * 4;          // 512KB
    int* hist = (int*)(ws + off);            off += (size_t)KC * 4;            // 8KB
    int* base_ = (int*)(ws + off);           off += (size_t)KC * 4;            // 8KB
    int* cursor = (int*)(ws + off);          off += (size_t)KC * 4;            // 8KB
    int* order = (int*)(ws + off);           off += (size_t)NPTS * 4;          // 512KB
    float* sums = (float*)(ws + off);        off += (size_t)KC * DIM * 4;      // 2MB

    hipMemsetAsync(sums, 0, (size_t)KC * DIM * sizeof(float), stream);
    cprep_kernel<<<KC / 4, 256, 0, stream>>>(cen, c_q, c_sq, hist);
    assign_kernel<<<NPTS / 128, 256, 0, stream>>>(x, c_q, c_sq, assigns, hist);
    scan_kernel<<<1, 256, 0, stream>>>(hist, base_, cursor);
    reorder_kernel<<<NPTS / 256, 256, 0, stream>>>(assigns, cursor, order);
    reduce_kernel<<<NPTS / 256, 256, 0, stream>>>(x, order, assigns, sums);
    finalize_kernel<<<KC * 64 / 256, 256, 0, stream>>>(sums, hist, cen, out);
}

// Round 6
// 610.456 us; speedup vs baseline: 1.8886x; 1.0536x over previous
//
#include <hip/hip_runtime.h>

typedef unsigned short u16;
typedef unsigned int u32;
typedef __attribute__((ext_vector_type(4)))  int  i32x4;
typedef __attribute__((ext_vector_type(16))) int  i32x16;
typedef __attribute__((ext_vector_type(16))) char i8x16;

#define NPTS 131072
#define DIM  256
#define KC   2048

// 3-level fixed point: v = S1*q1 + S2*q2 + S3*q3 + eps, |eps| <= S3/2 ~ 4.8e-7
// Ratio 254 => rint(r*INV) in [-127,127]: no clamp cascade.
// Identity S1*S3 == S2*S2 lets q2q2, q1q3, q3q1 share one accumulator.
constexpr float S1  = 0.0625f;                 // 127*S1 = 7.94 > max|N(0,1)|
constexpr float S2  = S1 / 254.0f;
constexpr float S3  = S2 * S2 / S1;            // = S2/254
constexpr float IS1 = 16.0f;
constexpr float IS2 = 4064.0f;                 // 254/S1
constexpr float IS3 = 1.0f / S3;
constexpr float W_A = S1 * S1;
// epilogue compares in W_A-scaled units: score' = 0.5*csq/W_A - (A + B/254 + C/254^2)
constexpr float R2  = 1.0f / 254.0f;
constexpr float R3  = 1.0f / 64516.0f;

__device__ inline void quant3(float v, char& q1, char& q2, char& q3) {
    float a = fminf(fmaxf(rintf(v * IS1), -127.f), 127.f);
    float r1 = fmaf(-a, S1, v);                // exact (pow2 scale)
    float b = fminf(fmaxf(rintf(r1 * IS2), -127.f), 127.f);
    float r2 = fmaf(-b, S2, r1);               // ~1-ulp error, absorbed by q3
    float c = fminf(fmaxf(rintf(r2 * IS3), -127.f), 127.f);
    q1 = (char)a; q2 = (char)b; q3 = (char)c;
}

// global -> LDS direct DMA, 16B per lane (wave-uniform base + lane*16)
#define GLD16(gsrc, ldst) \
    __builtin_amdgcn_global_load_lds( \
        (const __attribute__((address_space(1))) void*)(gsrc), \
        (__attribute__((address_space(3))) void*)(ldst), 16, 0, 0)

// ---------------------------------------------------------------------------
// Centroid prep: 3-level i8 split in MFMA-A-fragment order + scaled 0.5||c||^2.
// Per tile g (32 centroids): chunk s = dim/16, addr = ((g*16+s)*32+row)*16+b.
// Level l at byte offset l*KC*DIM. Also zeroes hist (blocks 0..7).
// ---------------------------------------------------------------------------
__global__ void cprep_kernel(const float* __restrict__ cen,
                             char* __restrict__ c_q,
                             float* __restrict__ c_sq,
                             int* __restrict__ hist) {
    if (blockIdx.x < 8) hist[blockIdx.x * 256 + threadIdx.x] = 0;
    const int lane = threadIdx.x & 63;
    const int wv   = threadIdx.x >> 6;
    const int n    = blockIdx.x * 4 + wv;               // centroid row
    float4 v = ((const float4*)(cen + (size_t)n * DIM))[lane];  // dims lane*4..+3
    float ss = v.x * v.x + v.y * v.y + v.z * v.z + v.w * v.w;
    float fv[4] = {v.x, v.y, v.z, v.w};
    char q1[4], q2[4], q3[4];
#pragma unroll
    for (int j = 0; j < 4; ++j) quant3(fv[j], q1[j], q2[j], q3[j]);
    const int g = n >> 5, r32 = n & 31;
    const int s = lane >> 2;                             // chunk = dim/16
    const size_t base = ((size_t)((g * 16 + s) * 32 + r32)) * 16 + (lane & 3) * 4;
    u32 p1 = (u32)(unsigned char)q1[0] | ((u32)(unsigned char)q1[1] << 8) |
             ((u32)(unsigned char)q1[2] << 16) | ((u32)(unsigned char)q1[3] << 24);
    u32 p2 = (u32)(unsigned char)q2[0] | ((u32)(unsigned char)q2[1] << 8) |
             ((u32)(unsigned char)q2[2] << 16) | ((u32)(unsigned char)q2[3] << 24);
    u32 p3 = (u32)(unsigned char)q3[0] | ((u32)(unsigned char)q3[1] << 8) |
             ((u32)(unsigned char)q3[2] << 16) | ((u32)(unsigned char)q3[3] << 24);
    *(u32*)(c_q + base) = p1;
    *(u32*)(c_q + (size_t)KC * DIM + base) = p2;
    *(u32*)(c_q + (size_t)2 * KC * DIM + base) = p3;
#pragma unroll
    for (int off = 32; off > 0; off >>= 1) ss += __shfl_xor(ss, off);
    if (lane == 0) c_sq[n] = 0.5f * ss / W_A;            // pre-scaled for epilogue
}

// ---------------------------------------------------------------------------
// Assignment: per wave 32 points x all 2048 centroids, 6 i8 MFMAs per k-tile:
//   accA += q1c*q1x                        (weight 1      in W_A units)
//   accB += q1c*q2x + q2c*q1x              (weight 1/254)
//   accC += q2c*q2x + q1c*q3x + q3c*q1x    (weight 1/254^2)
// launch_bounds(256,3): VGPR cap 170 fits true demand (~170) -> no spill,
// 3 blocks/CU (48KB LDS x 3 = 144KB <= 160KB) to cover dep/barrier stalls.
// ---------------------------------------------------------------------------
__global__ __launch_bounds__(256, 3) void assign_kernel(
    const float* __restrict__ x, const char* __restrict__ c_q,
    const float* __restrict__ c_sq, int* __restrict__ assigns,
    int* __restrict__ hist) {
    __shared__ char lds_c[2 * 24576];   // buf: [q1 8KB][q2 8KB][q3 8KB] x 2

    const int tid  = threadIdx.x;
    const int lane = tid & 63;
    const int wv   = tid >> 6;
    const int l31  = lane & 31;
    const int kh   = lane >> 5;         // 16-dim half of the 32-dim k-tile

    // ---- quantize this lane's point (dims kt*32+kh*16 .. +15 per kt) ----
    const int m = blockIdx.x * 128 + wv * 32 + l31;
    const float4* xr = (const float4*)(x + (size_t)m * DIM);
    i8x16 xq1[8], xq2[8], xq3[8];
#pragma unroll
    for (int kt = 0; kt < 8; ++kt) {
        float tmp[16];
#pragma unroll
        for (int j = 0; j < 4; ++j) {
            float4 f = xr[kt * 8 + kh * 4 + j];
            tmp[j * 4 + 0] = f.x; tmp[j * 4 + 1] = f.y;
            tmp[j * 4 + 2] = f.z; tmp[j * 4 + 3] = f.w;
        }
        i8x16 v1, v2, v3;
#pragma unroll
        for (int j = 0; j < 16; ++j) {
            char a, b, c;
            quant3(tmp[j], a, b, c);
            v1[j] = a; v2[j] = b; v3[j] = c;
        }
        xq1[kt] = v1; xq2[kt] = v2; xq3[kt] = v3;
    }

    const float4* csq4 = (const float4*)c_sq;
    float best = 3.4e38f;
    int bidx = 0;

    const char* cl2 = c_q + (size_t)KC * DIM;
    const char* cl3 = c_q + (size_t)2 * KC * DIM;
    // prologue: DMA tile 0 (6 x 16B per thread)
    {
        GLD16(c_q + tid * 16,         lds_c + tid * 16);
        GLD16(c_q + (tid + 256) * 16, lds_c + (tid + 256) * 16);
        GLD16(cl2 + tid * 16,         lds_c + 8192 + tid * 16);
        GLD16(cl2 + (tid + 256) * 16, lds_c + 8192 + (tid + 256) * 16);
        GLD16(cl3 + tid * 16,         lds_c + 16384 + tid * 16);
        GLD16(cl3 + (tid + 256) * 16, lds_c + 16384 + (tid + 256) * 16);
    }

    for (int nt = 0; nt < 64; ++nt) {
        const int b = nt & 1;
        __syncthreads();   // drains own DMA (vmcnt 0) -> tile nt visible to all
        if (nt < 63) {     // prefetch nt+1 into other buffer; hidden by compute
            const size_t so = (size_t)(nt + 1) * 8192;
            char* d = lds_c + (b ^ 1) * 24576;
            GLD16(c_q + so + tid * 16,         d + tid * 16);
            GLD16(c_q + so + (tid + 256) * 16, d + (tid + 256) * 16);
            GLD16(cl2 + so + tid * 16,         d + 8192 + tid * 16);
            GLD16(cl2 + so + (tid + 256) * 16, d + 8192 + (tid + 256) * 16);
            GLD16(cl3 + so + tid * 16,         d + 16384 + tid * 16);
            GLD16(cl3 + so + (tid + 256) * 16, d + 16384 + (tid + 256) * 16);
        }

        i32x16 accA = {}, accB = {}, accC = {};
        const char* cb = lds_c + b * 24576;
#pragma unroll
        for (int kt = 0; kt < 8; ++kt) {
            const int off = ((kt * 2 + kh) * 32 + l31) * 16;
            i32x4 c1 = __builtin_bit_cast(i32x4, *(const i8x16*)(cb + off));
            i32x4 c2 = __builtin_bit_cast(i32x4, *(const i8x16*)(cb + 8192 + off));
            i32x4 c3 = __builtin_bit_cast(i32x4, *(const i8x16*)(cb + 16384 + off));
            i32x4 x1 = __builtin_bit_cast(i32x4, xq1[kt]);
            i32x4 x2 = __builtin_bit_cast(i32x4, xq2[kt]);
            i32x4 x3 = __builtin_bit_cast(i32x4, xq3[kt]);
            // interleaved so same-accumulator MFMAs aren't back-to-back
            accA = __builtin_amdgcn_mfma_i32_32x32x32_i8(c1, x1, accA, 0, 0, 0);
            accB = __builtin_amdgcn_mfma_i32_32x32x32_i8(c1, x2, accB, 0, 0, 0);
            accC = __builtin_amdgcn_mfma_i32_32x32x32_i8(c2, x2, accC, 0, 0, 0);
            accB = __builtin_amdgcn_mfma_i32_32x32x32_i8(c2, x1, accB, 0, 0, 0);
            accC = __builtin_amdgcn_mfma_i32_32x32x32_i8(c1, x3, accC, 0, 0, 0);
            accC = __builtin_amdgcn_mfma_i32_32x32x32_i8(c3, x1, accC, 0, 0, 0);
        }

        // score' = csq_s - (A + B/254 + C/254^2) ; D row = (reg&3)+8*(reg>>2)+4*kh
#pragma unroll
        for (int bq = 0; bq < 4; ++bq) {
            float4 cs = csq4[nt * 8 + 2 * bq + kh];
            const int n0 = nt * 32 + 8 * bq + 4 * kh;
            float csa[4] = {cs.x, cs.y, cs.z, cs.w};
#pragma unroll
            for (int r = 0; r < 4; ++r) {
                const int idx = bq * 4 + r;
                float dot = fmaf((float)accB[idx], R2,
                            fmaf((float)accC[idx], R3, (float)accA[idx]));
                float v = csa[r] - dot;
                if (v < best) { best = v; bidx = n0 + r; }
            }
        }
    }

    // merge the lane pair holding the other 16 centroid rows for point m
    float oval = __shfl_xor(best, 32);
    int   oidx = __shfl_xor(bidx, 32);
    if (oval < best || (oval == best && oidx < bidx)) { best = oval; bidx = oidx; }
    if (lane < 32) {
        assigns[m] = bidx;
        atomicAdd(&hist[bidx], 1);   // 128 atomics/block; LDS staging gains nothing
    }
}

// Exclusive prefix sum over KC=2048 counts; one block of 256 threads x 8 each.
__global__ void scan_kernel(const int* __restrict__ hist,
                            int* __restrict__ base_,
                            int* __restrict__ cursor) {
    __shared__ int tmp[256];
    const int tid = threadIdx.x;
    int v[8], s = 0;
#pragma unroll
    for (int j = 0; j < 8; ++j) { v[j] = hist[tid * 8 + j]; s += v[j]; }
    tmp[tid] = s;
    __syncthreads();
    for (int off = 1; off < 256; off <<= 1) {
        int t = (tid >= off) ? tmp[tid - off] : 0;
        __syncthreads();
        tmp[tid] += t;
        __syncthreads();
    }
    int ex = tmp[tid] - s;
#pragma unroll
    for (int j = 0; j < 8; ++j) {
        base_[tid * 8 + j] = ex;
        cursor[tid * 8 + j] = ex;
        ex += v[j];
    }
}

__global__ void reorder_kernel(const int* __restrict__ assigns,
                               int* __restrict__ cursor,
                               int* __restrict__ order) {
    const int p = blockIdx.x * 256 + threadIdx.x;
    const int a = assigns[p];
    int pos = atomicAdd(&cursor[a], 1);
    order[pos] = p;
}

// ---------------------------------------------------------------------------
// Skew-immune segmented reduce: each block owns 256 consecutive rows of the
// SORTED order array; thread t owns dim t (coalesced 1KB row reads). Flush to
// sums[] with atomics only at cluster boundaries (block-uniform branches).
// ---------------------------------------------------------------------------
__global__ void reduce_kernel(const float* __restrict__ x,
                              const int* __restrict__ order,
                              const int* __restrict__ assigns,
                              float* __restrict__ sums) {
    const int tid = threadIdx.x;
    const int r0 = blockIdx.x * 256;
    float acc = 0.f;
    int cur = assigns[order[r0]];
    for (int r = 0; r < 256; r += 4) {
        int p0 = order[r0 + r + 0], p1 = order[r0 + r + 1];
        int p2 = order[r0 + r + 2], p3 = order[r0 + r + 3];
        float v0 = x[(size_t)p0 * DIM + tid];
        float v1 = x[(size_t)p1 * DIM + tid];
        float v2 = x[(size_t)p2 * DIM + tid];
        float v3 = x[(size_t)p3 * DIM + tid];
        int a0 = assigns[p0], a1 = assigns[p1], a2 = assigns[p2], a3 = assigns[p3];
        if (a0 != cur) { unsafeAtomicAdd(&sums[(size_t)cur * DIM + tid], acc); acc = 0.f; cur = a0; }
        acc += v0;
        if (a1 != cur) { unsafeAtomicAdd(&sums[(size_t)cur * DIM + tid], acc); acc = 0.f; cur = a1; }
        acc += v1;
        if (a2 != cur) { unsafeAtomicAdd(&sums[(size_t)cur * DIM + tid], acc); acc = 0.f; cur = a2; }
        acc += v2;
        if (a3 != cur) { unsafeAtomicAdd(&sums[(size_t)cur * DIM + tid], acc); acc = 0.f; cur = a3; }
        acc += v3;
    }
    unsafeAtomicAdd(&sums[(size_t)cur * DIM + tid], acc);
}

__global__ void finalize_kernel(const float* __restrict__ sums,
                                const int* __restrict__ hist,
                                const float* __restrict__ cen,
                                float* __restrict__ out) {
    const int id = blockIdx.x * 256 + threadIdx.x;   // KC*64 items
    const int k = id >> 6;
    const int cnt = hist[k];
    float4 s = ((const float4*)sums)[id];
    float4 c = ((const float4*)cen)[id];
    float4 o;
    if (cnt > 0) {
        float r = 1.0f / (float)cnt;
        o.x = s.x * r; o.y = s.y * r; o.z = s.z * r; o.w = s.w * r;
    } else {
        o = c;
    }
    ((float4*)out)[id] = o;
}

extern "C" void kernel_launch(void* const* d_in, const int* in_sizes, int n_in,
                              void* d_out, int out_size, void* d_ws, size_t ws_size,
                              hipStream_t stream) {
    (void)in_sizes; (void)n_in; (void)out_size; (void)ws_size;
    const float* x   = (const float*)d_in[0];
    const float* cen = (const float*)d_in[1];
    float* out = (float*)d_out;

    char* ws = (char*)d_ws;
    size_t off = 0;
    char* c_q = (char*)(ws + off);           off += (size_t)3 * KC * DIM;      // 1.5MB
    float* c_sq = (float*)(ws + off);        off += (size_t)KC * 4;            // 8KB
    int* assigns = (int*)(ws + off);         off += (size_t)NPTS * 4;          // 512KB
    int* hist = (int*)(ws + off);            off += (size_t)KC * 4;            // 8KB
    int* base_ = (int*)(ws + off);           off += (size_t)KC * 4;            // 8KB
    int* cursor = (int*)(ws + off);          off += (size_t)KC * 4;            // 8KB
    int* order = (int*)(ws + off);           off += (size_t)NPTS * 4;          // 512KB
    float* sums = (float*)(ws + off);        off += (size_t)KC * DIM * 4;      // 2MB

    hipMemsetAsync(sums, 0, (size_t)KC * DIM * sizeof(float), stream);
    cprep_kernel<<<KC / 4, 256, 0, stream>>>(cen, c_q, c_sq, hist);
    assign_kernel<<<NPTS / 128, 256, 0, stream>>>(x, c_q, c_sq, assigns, hist);
    scan_kernel<<<1, 256, 0, stream>>>(hist, base_, cursor);
    reorder_kernel<<<NPTS / 256, 256, 0, stream>>>(assigns, cursor, order);
    reduce_kernel<<<NPTS / 256, 256, 0, stream>>>(x, order, assigns, sums);
    finalize_kernel<<<KC * 64 / 256, 256, 0, stream>>>(sums, hist, cen, out);
}